// Round 1
// baseline (1682.299 us; speedup 1.0000x reference)
//
#include <hip/hip_runtime.h>
#include <cstdint>

#define B 4096
#define D 256
#define H 512
#define K 10
#define NL 4
#define S 10
#define NOUT 30           // used head columns per d (3*K); tail C=64 unused
#define HEADW 94          // 3*K + C
#define ND (B*D)          // 1048576

// ---------------- threefry2x32 (JAX-exact) ----------------
__host__ __device__ inline void threefry2x32(uint32_t k0, uint32_t k1,
                                             uint32_t x0, uint32_t x1,
                                             uint32_t& o0, uint32_t& o1) {
  uint32_t ks2 = k0 ^ k1 ^ 0x1BD11BDAu;
#define TF_ROT(x, r) (((x) << (r)) | ((x) >> (32 - (r))))
#define TF_RND(r) { x0 += x1; x1 = TF_ROT(x1, r); x1 ^= x0; }
  x0 += k0; x1 += k1;
  TF_RND(13) TF_RND(15) TF_RND(26) TF_RND(6)
  x0 += k1; x1 += ks2 + 1u;
  TF_RND(17) TF_RND(29) TF_RND(16) TF_RND(24)
  x0 += ks2; x1 += k0 + 2u;
  TF_RND(13) TF_RND(15) TF_RND(26) TF_RND(6)
  x0 += k0; x1 += k1 + 3u;
  TF_RND(17) TF_RND(29) TF_RND(16) TF_RND(24)
  x0 += k1; x1 += ks2 + 4u;
  TF_RND(13) TF_RND(15) TF_RND(26) TF_RND(6)
  x0 += ks2; x1 += k0 + 5u;
  o0 = x0; o1 = x1;
#undef TF_RND
#undef TF_ROT
}

// partitionable-mode 32-bit random bits: xor of the two threefry outputs,
// counter = (hi=0, lo=flat_index) since all sizes < 2^32
__device__ __forceinline__ uint32_t rb32(uint32_t k0, uint32_t k1, uint32_t idx) {
  uint32_t a, b;
  threefry2x32(k0, k1, 0u, idx, a, b);
  return a ^ b;
}

__device__ __forceinline__ float u01_from_bits(uint32_t bits) {
  return __uint_as_float((bits >> 9) | 0x3f800000u) - 1.0f;  // [0,1)
}

// XLA ErfInv32 (Giles single-precision polynomial)
__device__ __forceinline__ float erfinv_f32(float x) {
  float w = -log1pf(-x * x);
  float p;
  if (w < 5.0f) {
    w = w - 2.5f;
    p = 2.81022636e-08f;
    p = fmaf(p, w, 3.43273939e-07f);
    p = fmaf(p, w, -3.5233877e-06f);
    p = fmaf(p, w, -4.39150654e-06f);
    p = fmaf(p, w, 0.00021858087f);
    p = fmaf(p, w, -0.00125372503f);
    p = fmaf(p, w, -0.00417768164f);
    p = fmaf(p, w, 0.246640727f);
    p = fmaf(p, w, 1.50140941f);
  } else {
    w = sqrtf(w) - 3.0f;
    p = -0.000200214257f;
    p = fmaf(p, w, 0.000100950558f);
    p = fmaf(p, w, 0.00134934322f);
    p = fmaf(p, w, -0.00367342844f);
    p = fmaf(p, w, 0.00573950773f);
    p = fmaf(p, w, -0.0076224613f);
    p = fmaf(p, w, 0.00943887047f);
    p = fmaf(p, w, 1.00167406f);
    p = fmaf(p, w, 2.83297682f);
  }
  return p * x;
}

// ---------------- kernels ----------------
__global__ __launch_bounds__(256) void prep_kernel(const float* __restrict__ x,
                                                   const float* __restrict__ mask,
                                                   float* __restrict__ xcat) {
  int i = blockIdx.x * 256 + threadIdx.x;  // over B*512
  if (i >= B * 2 * D) return;
  int b = i >> 9, c = i & 511;
  float v = (c < D) ? x[b * D + c] * mask[b * D + c] : mask[b * D + (c - D)];
  xcat[i] = v;
}

// C(4096x512) = [relu?](A) @ W(512x512) + bias [+ res]
template <int RELU, int RES>
__global__ __launch_bounds__(256) void gemm512(const float* __restrict__ A,
                                               const float* __restrict__ W,
                                               const float* __restrict__ bias,
                                               const float* res, float* C) {
  __shared__ float As[16][65];
  __shared__ float Ws[16][65];
  const int bm = blockIdx.y * 64, bn = blockIdx.x * 64;
  const int tid = threadIdx.x;
  const int tx = tid & 15, ty = tid >> 4;
  float acc[4][4] = {};
  for (int k0 = 0; k0 < H; k0 += 16) {
#pragma unroll
    for (int i = 0; i < 4; ++i) {
      int e = tid + 256 * i;  // 1024 elements
      int m = e >> 4, k = e & 15;
      float v = A[(size_t)(bm + m) * H + k0 + k];
      if (RELU) v = fmaxf(v, 0.0f);
      As[k][m] = v;
    }
#pragma unroll
    for (int i = 0; i < 4; ++i) {
      int e = tid + 256 * i;
      int k = e >> 6, n = e & 63;
      Ws[k][n] = W[(size_t)(k0 + k) * H + bn + n];
    }
    __syncthreads();
#pragma unroll
    for (int kk = 0; kk < 16; ++kk) {
      float a[4], w[4];
#pragma unroll
      for (int i = 0; i < 4; ++i) a[i] = As[kk][ty * 4 + i];
#pragma unroll
      for (int j = 0; j < 4; ++j) w[j] = Ws[kk][tx * 4 + j];
#pragma unroll
      for (int i = 0; i < 4; ++i)
#pragma unroll
        for (int j = 0; j < 4; ++j) acc[i][j] = fmaf(a[i], w[j], acc[i][j]);
    }
    __syncthreads();
  }
#pragma unroll
  for (int i = 0; i < 4; ++i) {
    int row = bm + ty * 4 + i;
#pragma unroll
    for (int j = 0; j < 4; ++j) {
      int col = bn + tx * 4 + j;
      float v = acc[i][j] + bias[col];
      if (RES) v = res[(size_t)row * H + col] + v;  // h + r, ref order
      C[(size_t)row * H + col] = v;
    }
  }
}

// head(4096 x 7680) = A(4096x512) @ Wfin-gathered + bfin, softplus on cols 20..29 of each 30
__global__ __launch_bounds__(256) void gemm_fin(const float* __restrict__ A,
                                                const float* __restrict__ Wf,
                                                const float* __restrict__ bf,
                                                float* __restrict__ headout) {
  __shared__ float As[16][65];
  __shared__ float Ws[16][65];
  const int bm = blockIdx.y * 64, bn = blockIdx.x * 64;  // bn over D*NOUT=7680
  const int tid = threadIdx.x;
  const int tx = tid & 15, ty = tid >> 4;
  float acc[4][4] = {};
  for (int k0 = 0; k0 < H; k0 += 16) {
#pragma unroll
    for (int i = 0; i < 4; ++i) {
      int e = tid + 256 * i;
      int m = e >> 4, k = e & 15;
      As[k][m] = A[(size_t)(bm + m) * H + k0 + k];
    }
#pragma unroll
    for (int i = 0; i < 4; ++i) {
      int e = tid + 256 * i;
      int k = e >> 6, n = e & 63;
      int c = bn + n;
      int dd = c / NOUT, j = c - dd * NOUT;
      Ws[k][n] = Wf[(size_t)(k0 + k) * (D * HEADW) + dd * HEADW + j];
    }
    __syncthreads();
#pragma unroll
    for (int kk = 0; kk < 16; ++kk) {
      float a[4], w[4];
#pragma unroll
      for (int i = 0; i < 4; ++i) a[i] = As[kk][ty * 4 + i];
#pragma unroll
      for (int j = 0; j < 4; ++j) w[j] = Ws[kk][tx * 4 + j];
#pragma unroll
      for (int i = 0; i < 4; ++i)
#pragma unroll
        for (int j = 0; j < 4; ++j) acc[i][j] = fmaf(a[i], w[j], acc[i][j]);
    }
    __syncthreads();
  }
#pragma unroll
  for (int i = 0; i < 4; ++i) {
    int row = bm + ty * 4 + i;
#pragma unroll
    for (int j4 = 0; j4 < 4; ++j4) {
      int c = bn + tx * 4 + j4;
      int dd = c / NOUT, j = c - dd * NOUT;
      float v = acc[i][j4] + bf[dd * HEADW + j];
      if (j >= 2 * K) {  // scales = softplus(v) + 0.001 ; softplus = max(v,0)+log1p(exp(-|v|))
        v = (fmaxf(v, 0.0f) + log1pf(expf(-fabsf(v)))) + 0.001f;
      }
      headout[(size_t)row * (D * NOUT) + c] = v;
    }
  }
}

__global__ __launch_bounds__(256) void ll_mean_kernel(const float* __restrict__ head,
                                                      const float* __restrict__ x,
                                                      const float* __restrict__ mask,
                                                      float* __restrict__ out_ll,
                                                      float* __restrict__ out_mean) {
  int idx = blockIdx.x * 256 + threadIdx.x;  // b*D + d
  if (idx >= ND) return;
  const float* hp = head + (size_t)idx * NOUT;
  float lg[K], mn[K], sc[K];
#pragma unroll
  for (int k = 0; k < K; ++k) { lg[k] = hp[k]; mn[k] = hp[K + k]; sc[k] = hp[2 * K + k]; }
  float q = 1.0f - mask[idx];
  float xu = x[idx] * q;
  float m = lg[0];
#pragma unroll
  for (int k = 1; k < K; ++k) m = fmaxf(m, lg[k]);
  float e[K];
  float sum = 0.0f;
#pragma unroll
  for (int k = 0; k < K; ++k) { e[k] = expf(lg[k] - m); sum += e[k]; }
  float lse = logf(sum);
  float a[K];
  float amax = -3.402823466e38f;
#pragma unroll
  for (int k = 0; k < K; ++k) {
    float z = (xu - mn[k]) / sc[k];
    float cll = -0.5f * z * z - logf(sc[k]) - 0.9189385332046727f;  // 0.5*log(2*pi)
    float lw = (lg[k] - m) - lse;                                    // log_softmax
    a[k] = lw + cll;
    amax = fmaxf(amax, a[k]);
  }
  float s2 = 0.0f;
#pragma unroll
  for (int k = 0; k < K; ++k) s2 += expf(a[k] - amax);
  out_ll[idx] = (logf(s2) + amax) * q;
  float pm = 0.0f;
#pragma unroll
  for (int k = 0; k < K; ++k) pm += (e[k] / sum) * mn[k];
  out_mean[idx] = pm * q;
}

__global__ __launch_bounds__(256) void sample_kernel(const float* __restrict__ head,
                                                     const float* __restrict__ mask,
                                                     float* __restrict__ out_s,
                                                     uint32_t kc0, uint32_t kc1,
                                                     uint32_t kn0, uint32_t kn1) {
  int idx = blockIdx.x * 256 + threadIdx.x;  // b*D + d
  if (idx >= ND) return;
  int b = idx / D, d = idx - b * D;
  float q = 1.0f - mask[idx];
  const float* hp = head + (size_t)idx * NOUT;
  float lg[K];
#pragma unroll
  for (int k = 0; k < K; ++k) lg[k] = hp[k];
  for (int s = 0; s < S; ++s) {
    // gumbel flat index for (s,b,d,k) in (S,B,D,K)
    uint32_t base = ((uint32_t)s * (uint32_t)ND + (uint32_t)idx) * (uint32_t)K;
    int best = 0;
    float vbest = -3.402823466e38f;
#pragma unroll
    for (int k = 0; k < K; ++k) {
      uint32_t bits = rb32(kc0, kc1, base + (uint32_t)k);
      float f = fmaxf(u01_from_bits(bits), 1.17549435e-38f);  // uniform(tiny, 1)
      float g = -logf(-logf(f));
      float v = g + lg[k];
      if (v > vbest) { vbest = v; best = k; }  // first-max tie-break like argmax
    }
    uint32_t ebits = rb32(kn0, kn1, (uint32_t)s * (uint32_t)ND + (uint32_t)idx);
    float f = u01_from_bits(ebits);
    float r = f * 2.0f + (-0.99999994f);          // uniform(nextafter(-1,0), 1)
    r = fmaxf(r, -0.99999994f);
    float eps = 1.4142135623730951f * erfinv_f32(r);
    float mu = hp[K + best];
    float sg = hp[2 * K + best];
    float prod = sg * eps;
    float sam = (mu + prod) * q;
    out_s[((size_t)b * S + s) * D + d] = sam;  // (B,S,D) layout
  }
}

// ---------------- launch ----------------
extern "C" void kernel_launch(void* const* d_in, const int* in_sizes, int n_in,
                              void* d_out, int out_size, void* d_ws, size_t ws_size,
                              hipStream_t stream) {
  const float* x    = (const float*)d_in[0];
  const float* mask = (const float*)d_in[1];
  const float* W_in = (const float*)d_in[2];
  const float* b_in = (const float*)d_in[3];
  const float* W1   = (const float*)d_in[4];
  const float* b1   = (const float*)d_in[5];
  const float* W2   = (const float*)d_in[6];
  const float* b2   = (const float*)d_in[7];
  const float* Wf   = (const float*)d_in[8];
  const float* bf   = (const float*)d_in[9];
  // d_in[10] = num_importance_samples (S=10, compile-time constant)

  float* ws   = (float*)d_ws;
  float* xcat = ws;                         // B*512
  float* h    = xcat + (size_t)B * 512;     // B*H
  float* t    = h + (size_t)B * H;          // B*H
  float* head = t + (size_t)B * H;          // B*D*NOUT = 31,457,280 floats
  // total ws use: 150,994,944 bytes

  float* out_ll   = (float*)d_out;                   // (B,D)
  float* out_s    = out_ll + (size_t)ND;             // (B,S,D)
  float* out_mean = out_s + (size_t)ND * S;          // (B,D)

  prep_kernel<<<(B * 2 * D) / 256, 256, 0, stream>>>(x, mask, xcat);

  dim3 g512(H / 64, B / 64);
  gemm512<0, 0><<<g512, 256, 0, stream>>>(xcat, W_in, b_in, nullptr, h);
  for (int l = 0; l < NL; ++l) {
    gemm512<1, 0><<<g512, 256, 0, stream>>>(h, W1 + (size_t)l * H * H, b1 + (size_t)l * H,
                                            nullptr, t);
    gemm512<1, 1><<<g512, 256, 0, stream>>>(t, W2 + (size_t)l * H * H, b2 + (size_t)l * H,
                                            h, h);  // h = h + r (in-place safe)
  }

  dim3 gf((D * NOUT) / 64, B / 64);
  gemm_fin<<<gf, 256, 0, stream>>>(h, Wf, bf, head);

  ll_mean_kernel<<<ND / 256, 256, 0, stream>>>(head, x, mask, out_ll, out_mean);

  // JAX RNG: key(1234) -> [0,1234]; foldlike split: kc = tf(key,(0,0)), kn = tf(key,(0,1))
  uint32_t kc0, kc1, kn0, kn1;
  threefry2x32(0u, 1234u, 0u, 0u, kc0, kc1);
  threefry2x32(0u, 1234u, 0u, 1u, kn0, kn1);
  sample_kernel<<<ND / 256, 256, 0, stream>>>(head, mask, out_s, kc0, kc1, kn0, kn1);
}

// Round 4
// 1331.533 us; speedup vs baseline: 1.2634x; 1.2634x over previous
//
#include <hip/hip_runtime.h>
#include <cstdint>

#define B 4096
#define D 256
#define H 512
#define K 10
#define NL 4
#define S 10
#define NOUT 30           // used head columns per d (3*K); tail C=64 unused
#define HEADW 94          // 3*K + C
#define ND (B*D)          // 1048576
#define NFIN 7680         // D*NOUT

// ---------------- threefry2x32 (JAX-exact) ----------------
__host__ __device__ inline void threefry2x32(uint32_t k0, uint32_t k1,
                                             uint32_t x0, uint32_t x1,
                                             uint32_t& o0, uint32_t& o1) {
  uint32_t ks2 = k0 ^ k1 ^ 0x1BD11BDAu;
#define TF_ROT(x, r) (((x) << (r)) | ((x) >> (32 - (r))))
#define TF_RND(r) { x0 += x1; x1 = TF_ROT(x1, r); x1 ^= x0; }
  x0 += k0; x1 += k1;
  TF_RND(13) TF_RND(15) TF_RND(26) TF_RND(6)
  x0 += k1; x1 += ks2 + 1u;
  TF_RND(17) TF_RND(29) TF_RND(16) TF_RND(24)
  x0 += ks2; x1 += k0 + 2u;
  TF_RND(13) TF_RND(15) TF_RND(26) TF_RND(6)
  x0 += k0; x1 += k1 + 3u;
  TF_RND(17) TF_RND(29) TF_RND(16) TF_RND(24)
  x0 += k1; x1 += ks2 + 4u;
  TF_RND(13) TF_RND(15) TF_RND(26) TF_RND(6)
  x0 += ks2; x1 += k0 + 5u;
  o0 = x0; o1 = x1;
#undef TF_RND
#undef TF_ROT
}

__device__ __forceinline__ uint32_t rb32(uint32_t k0, uint32_t k1, uint32_t idx) {
  uint32_t a, b;
  threefry2x32(k0, k1, 0u, idx, a, b);
  return a ^ b;
}

__device__ __forceinline__ float u01_from_bits(uint32_t bits) {
  return __uint_as_float((bits >> 9) | 0x3f800000u) - 1.0f;  // [0,1)
}

// XLA ErfInv32 (Giles single-precision polynomial)
__device__ __forceinline__ float erfinv_f32(float x) {
  float w = -log1pf(-x * x);
  float p;
  if (w < 5.0f) {
    w = w - 2.5f;
    p = 2.81022636e-08f;
    p = fmaf(p, w, 3.43273939e-07f);
    p = fmaf(p, w, -3.5233877e-06f);
    p = fmaf(p, w, -4.39150654e-06f);
    p = fmaf(p, w, 0.00021858087f);
    p = fmaf(p, w, -0.00125372503f);
    p = fmaf(p, w, -0.00417768164f);
    p = fmaf(p, w, 0.246640727f);
    p = fmaf(p, w, 1.50140941f);
  } else {
    w = sqrtf(w) - 3.0f;
    p = -0.000200214257f;
    p = fmaf(p, w, 0.000100950558f);
    p = fmaf(p, w, 0.00134934322f);
    p = fmaf(p, w, -0.00367342844f);
    p = fmaf(p, w, 0.00573950773f);
    p = fmaf(p, w, -0.0076224613f);
    p = fmaf(p, w, 0.00943887047f);
    p = fmaf(p, w, 1.00167406f);
    p = fmaf(p, w, 2.83297682f);
  }
  return p * x;
}

// ---------------- async global->LDS (16B/lane) ----------------
__device__ __forceinline__ void gload16(const void* g, void* l) {
  __builtin_amdgcn_global_load_lds(
      (const __attribute__((address_space(1))) void*)g,
      (__attribute__((address_space(3))) void*)l, 16, 0, 0);
}

// ---------------- prep: xcat = [x*mask, mask]  (bit-identical to R1) ------
__global__ __launch_bounds__(256) void prep_kernel(const float* __restrict__ x,
                                                   const float* __restrict__ mask,
                                                   float* __restrict__ xcat) {
  int i = blockIdx.x * 256 + threadIdx.x;  // over B*512
  if (i >= B * 2 * D) return;
  int b = i >> 9, c = i & 511;
  float v = (c < D) ? x[b * D + c] * mask[b * D + c] : mask[b * D + (c - D)];
  xcat[i] = v;
}

// ---------------- fin weight gather: wsg[k][c] = Wf[k][(c/30)*94 + c%30] ---
__global__ __launch_bounds__(256) void wgather(const float* __restrict__ Wf,
                                               float* __restrict__ wsg) {
  int c = blockIdx.x * 256 + threadIdx.x;  // 0..7679
  int k = blockIdx.y;                      // 0..511
  int dd = c / NOUT, j = c - dd * NOUT;
  wsg[(size_t)k * NFIN + c] = Wf[(size_t)k * (D * HEADW) + dd * HEADW + j];
}

// ---------------- fp32 trunk GEMM (bit-identical chains to R1) ----------
// C(4096x512) = [relu?](A) @ W(512x512) + bias [+ res]
// 64x64 tile, BK=32, 256 threads, 4x4/thread. Per-output accumulation is
// ONE fmaf chain over ascending k -> bit-identical to R1's gemm512.
template <int RELU, int RES>
__global__ __launch_bounds__(256) void gemm_trunk(const float* __restrict__ A,
                                                  const float* __restrict__ W,
                                                  const float* __restrict__ bias,
                                                  const float* res, float* C) {
  __shared__ float As[32 * 68];  // [k][m], stride 68 (272B, 16B-aligned)
  __shared__ float Ws[32 * 64];  // [k][n], stride 64
  const int tid = threadIdx.x;
  const int lane = tid & 63, wid = tid >> 6;
  const int tx = tid & 15, ty = tid >> 4;
  const int bm = blockIdx.y * 64, bn = blockIdx.x * 64;
  const int ls = tid & 7, lm = tid >> 3;  // A-load: k-slot, row

  float acc[4][4] = {};

  for (int k0 = 0; k0 < H; k0 += 32) {
    // B: direct global->LDS, [k][n] rows contiguous (wave-contiguous dest)
#pragma unroll
    for (int c = wid; c < 8; c += 4) {
      gload16(W + (size_t)(k0 + c * 4 + (lane >> 4)) * H + bn + (lane & 15) * 4,
              Ws + c * 256 + lane * 4);
    }
    // A: load float4 along k, transpose into [k][m] via ds_write
#pragma unroll
    for (int r = 0; r < 2; ++r) {
      int m = lm + 32 * r;
      float4 f = *(const float4*)(A + (size_t)(bm + m) * H + k0 + 4 * ls);
      if (RELU) {
        f.x = fmaxf(f.x, 0.0f); f.y = fmaxf(f.y, 0.0f);
        f.z = fmaxf(f.z, 0.0f); f.w = fmaxf(f.w, 0.0f);
      }
      As[(4 * ls + 0) * 68 + m] = f.x;
      As[(4 * ls + 1) * 68 + m] = f.y;
      As[(4 * ls + 2) * 68 + m] = f.z;
      As[(4 * ls + 3) * 68 + m] = f.w;
    }
    __syncthreads();
#pragma unroll
    for (int kk = 0; kk < 32; ++kk) {
      float4 a4 = *(const float4*)(As + kk * 68 + ty * 4);
      float4 b4 = *(const float4*)(Ws + kk * 64 + tx * 4);
      float a[4] = {a4.x, a4.y, a4.z, a4.w};
      float b[4] = {b4.x, b4.y, b4.z, b4.w};
#pragma unroll
      for (int i = 0; i < 4; ++i)
#pragma unroll
        for (int j = 0; j < 4; ++j) acc[i][j] = fmaf(a[i], b[j], acc[i][j]);
    }
    __syncthreads();
  }
#pragma unroll
  for (int i = 0; i < 4; ++i) {
    int row = bm + ty * 4 + i;
#pragma unroll
    for (int j = 0; j < 4; ++j) {
      int col = bn + tx * 4 + j;
      float v = acc[i][j] + bias[col];
      if (RES) v = res[(size_t)row * H + col] + v;  // same order as R1
      C[(size_t)row * H + col] = v;
    }
  }
}

// ---------------- fp32 fin GEMM (bit-identical chains to R1 gemm_fin) ----
// head(4096x7680) = h @ wsg + bf(gathered), softplus on cols 20..29 per d
// 128x128 tile, BK=32, 256 threads, 8x8/thread.
__global__ __launch_bounds__(256) void gemm_fin(const float* __restrict__ A,
                                                const float* __restrict__ Wg,
                                                const float* __restrict__ bf,
                                                float* __restrict__ headout) {
  __shared__ float As[32 * 136];  // [k][m], stride 136 (544B, 16B-aligned)
  __shared__ float Ws[32 * 128];  // [k][n], stride 128
  const int tid = threadIdx.x;
  const int lane = tid & 63, wid = tid >> 6;
  const int tx = tid & 15, ty = tid >> 4;
  const int bm = blockIdx.y * 128, bn = blockIdx.x * 128;
  const int ls = tid & 7, lm = tid >> 3;

  float acc[8][8] = {};

  for (int k0 = 0; k0 < H; k0 += 32) {
#pragma unroll
    for (int c = wid; c < 16; c += 4) {
      gload16(Wg + (size_t)(k0 + c * 2 + (lane >> 5)) * NFIN + bn + (lane & 31) * 4,
              Ws + c * 256 + lane * 4);
    }
#pragma unroll
    for (int r = 0; r < 4; ++r) {
      int m = lm + 32 * r;
      float4 f = *(const float4*)(A + (size_t)(bm + m) * H + k0 + 4 * ls);
      As[(4 * ls + 0) * 136 + m] = f.x;
      As[(4 * ls + 1) * 136 + m] = f.y;
      As[(4 * ls + 2) * 136 + m] = f.z;
      As[(4 * ls + 3) * 136 + m] = f.w;
    }
    __syncthreads();
#pragma unroll
    for (int kk = 0; kk < 32; ++kk) {
      float a[8], b[8];
      *(float4*)(a + 0) = *(const float4*)(As + kk * 136 + ty * 8);
      *(float4*)(a + 4) = *(const float4*)(As + kk * 136 + ty * 8 + 4);
      *(float4*)(b + 0) = *(const float4*)(Ws + kk * 128 + tx * 8);
      *(float4*)(b + 4) = *(const float4*)(Ws + kk * 128 + tx * 8 + 4);
#pragma unroll
      for (int i = 0; i < 8; ++i)
#pragma unroll
        for (int j = 0; j < 8; ++j) acc[i][j] = fmaf(a[i], b[j], acc[i][j]);
    }
    __syncthreads();
  }
#pragma unroll
  for (int i = 0; i < 8; ++i) {
    int row = bm + ty * 8 + i;
#pragma unroll
    for (int j = 0; j < 8; ++j) {
      int c = bn + tx * 8 + j;
      int dd = c / NOUT, jj = c - dd * NOUT;
      float v = acc[i][j] + bf[dd * HEADW + jj];
      if (jj >= 2 * K) {  // softplus + 0.001, exact same expr as R1
        v = (fmaxf(v, 0.0f) + log1pf(expf(-fabsf(v)))) + 0.001f;
      }
      headout[(size_t)row * NFIN + c] = v;
    }
  }
}

// ---------------- tail kernels (verbatim R1/R2 arithmetic) ----------------
__global__ __launch_bounds__(256) void ll_mean_kernel(const float* __restrict__ head,
                                                      const float* __restrict__ x,
                                                      const float* __restrict__ mask,
                                                      float* __restrict__ out_ll,
                                                      float* __restrict__ out_mean) {
  int idx = blockIdx.x * 256 + threadIdx.x;  // b*D + d
  if (idx >= ND) return;
  const float* hp = head + (size_t)idx * NOUT;
  float lg[K], mn[K], sc[K];
#pragma unroll
  for (int k = 0; k < K; ++k) { lg[k] = hp[k]; mn[k] = hp[K + k]; sc[k] = hp[2 * K + k]; }
  float q = 1.0f - mask[idx];
  float xu = x[idx] * q;
  float m = lg[0];
#pragma unroll
  for (int k = 1; k < K; ++k) m = fmaxf(m, lg[k]);
  float e[K];
  float sum = 0.0f;
#pragma unroll
  for (int k = 0; k < K; ++k) { e[k] = expf(lg[k] - m); sum += e[k]; }
  float lse = logf(sum);
  float a[K];
  float amax = -3.402823466e38f;
#pragma unroll
  for (int k = 0; k < K; ++k) {
    float z = (xu - mn[k]) / sc[k];
    float cll = -0.5f * z * z - logf(sc[k]) - 0.9189385332046727f;
    float lw = (lg[k] - m) - lse;
    a[k] = lw + cll;
    amax = fmaxf(amax, a[k]);
  }
  float s2 = 0.0f;
#pragma unroll
  for (int k = 0; k < K; ++k) s2 += expf(a[k] - amax);
  out_ll[idx] = (logf(s2) + amax) * q;
  float pm = 0.0f;
#pragma unroll
  for (int k = 0; k < K; ++k) pm += (e[k] / sum) * mn[k];
  out_mean[idx] = pm * q;
}

__global__ __launch_bounds__(256) void sample_kernel(const float* __restrict__ head,
                                                     const float* __restrict__ mask,
                                                     float* __restrict__ out_s,
                                                     uint32_t kc0, uint32_t kc1,
                                                     uint32_t kn0, uint32_t kn1) {
  int tid = blockIdx.x * 256 + threadIdx.x;  // s*ND + idx
  if (tid >= ND * S) return;
  int s = tid >> 20;            // / ND
  int idx = tid & (ND - 1);     // % ND
  int b = idx >> 8, d = idx & (D - 1);
  float q = 1.0f - mask[idx];
  const float* hp = head + (size_t)idx * NOUT;
  uint32_t base = (uint32_t)tid * (uint32_t)K;
  int best = 0;
  float vbest = -3.402823466e38f;
#pragma unroll
  for (int k = 0; k < K; ++k) {
    uint32_t bits = rb32(kc0, kc1, base + (uint32_t)k);
    float f = fmaxf(u01_from_bits(bits), 1.17549435e-38f);
    float g = -logf(-logf(f));
    float v = g + hp[k];
    if (v > vbest) { vbest = v; best = k; }
  }
  uint32_t ebits = rb32(kn0, kn1, (uint32_t)tid);
  float f = u01_from_bits(ebits);
  float r = f * 2.0f + (-0.99999994f);
  r = fmaxf(r, -0.99999994f);
  float eps = 1.4142135623730951f * erfinv_f32(r);
  float mu = hp[K + best];
  float sg = hp[2 * K + best];
  out_s[((size_t)b * S + s) * D + d] = (mu + sg * eps) * q;
}

// ---------------- launch ----------------
extern "C" void kernel_launch(void* const* d_in, const int* in_sizes, int n_in,
                              void* d_out, int out_size, void* d_ws, size_t ws_size,
                              hipStream_t stream) {
  const float* x    = (const float*)d_in[0];
  const float* mask = (const float*)d_in[1];
  const float* W_in = (const float*)d_in[2];
  const float* b_in = (const float*)d_in[3];
  const float* W1   = (const float*)d_in[4];
  const float* b1   = (const float*)d_in[5];
  const float* W2   = (const float*)d_in[6];
  const float* b2   = (const float*)d_in[7];
  const float* Wf   = (const float*)d_in[8];
  const float* bf   = (const float*)d_in[9];

  // workspace: head 125,829,120 + h 8,388,608 + wsg 15,728,640 = 149,946,368 B
  // (<= 150,994,944 proven in R1). xcat and t alias head (disjoint lifetimes).
  char* w = (char*)d_ws;
  float* head = (float*)w;                      // B*7680 f32
  float* xcat = head;                           // alias: dead after gemm0
  float* t    = head;                           // alias: dead before fin
  float* h    = (float*)(w + 125829120);        // B*512 f32 (live through fin)
  float* wsg  = (float*)(w + 134217728);        // 512*7680 f32 gathered Wf

  float* out_ll   = (float*)d_out;              // (B,D)
  float* out_s    = out_ll + (size_t)ND;        // (B,S,D)
  float* out_mean = out_s + (size_t)ND * S;     // (B,D)

  // independent: gather fin weights once
  wgather<<<dim3(NFIN / 256, 512), 256, 0, stream>>>(Wf, wsg);

  prep_kernel<<<(B * 2 * D) / 256, 256, 0, stream>>>(x, mask, xcat);

  dim3 gtr(H / 64, B / 64);  // (8, 64) = 512 blocks
  gemm_trunk<0, 0><<<gtr, 256, 0, stream>>>(xcat, W_in, b_in, nullptr, h);
  for (int l = 0; l < NL; ++l) {
    gemm_trunk<1, 0><<<gtr, 256, 0, stream>>>(h, W1 + (size_t)l * H * H,
                                              b1 + (size_t)l * H, nullptr, t);
    gemm_trunk<1, 1><<<gtr, 256, 0, stream>>>(t, W2 + (size_t)l * H * H,
                                              b2 + (size_t)l * H, h, h);
  }

  gemm_fin<<<dim3(NFIN / 128, B / 128), 256, 0, stream>>>(h, wsg, bf, head);

  ll_mean_kernel<<<ND / 256, 256, 0, stream>>>(head, x, mask, out_ll, out_mean);

  uint32_t kc0, kc1, kn0, kn1;
  threefry2x32(0u, 1234u, 0u, 0u, kc0, kc1);
  threefry2x32(0u, 1234u, 0u, 1u, kn0, kn1);
  sample_kernel<<<(ND * S) / 256, 256, 0, stream>>>(head, mask, out_s, kc0, kc1, kn0, kn1);
}

// Round 5
// 1321.527 us; speedup vs baseline: 1.2730x; 1.0076x over previous
//
#include <hip/hip_runtime.h>
#include <cstdint>

#define B 4096
#define D 256
#define H 512
#define K 10
#define NL 4
#define S 10
#define NOUT 30           // used head columns per d (3*K); tail C=64 unused
#define HEADW 94          // 3*K + C
#define ND (B*D)          // 1048576
#define NFIN 7680         // D*NOUT
#define NLOG 2560         // D*K   logits columns (exact fp32)
#define NMS  5120         // D*2K  means+scales columns (MFMA path)

typedef __bf16 bf16x8 __attribute__((ext_vector_type(8)));
typedef float  f32x16 __attribute__((ext_vector_type(16)));

// ---------------- threefry2x32 (JAX-exact) ----------------
__host__ __device__ inline void threefry2x32(uint32_t k0, uint32_t k1,
                                             uint32_t x0, uint32_t x1,
                                             uint32_t& o0, uint32_t& o1) {
  uint32_t ks2 = k0 ^ k1 ^ 0x1BD11BDAu;
#define TF_ROT(x, r) (((x) << (r)) | ((x) >> (32 - (r))))
#define TF_RND(r) { x0 += x1; x1 = TF_ROT(x1, r); x1 ^= x0; }
  x0 += k0; x1 += k1;
  TF_RND(13) TF_RND(15) TF_RND(26) TF_RND(6)
  x0 += k1; x1 += ks2 + 1u;
  TF_RND(17) TF_RND(29) TF_RND(16) TF_RND(24)
  x0 += ks2; x1 += k0 + 2u;
  TF_RND(13) TF_RND(15) TF_RND(26) TF_RND(6)
  x0 += k0; x1 += k1 + 3u;
  TF_RND(17) TF_RND(29) TF_RND(16) TF_RND(24)
  x0 += k1; x1 += ks2 + 4u;
  TF_RND(13) TF_RND(15) TF_RND(26) TF_RND(6)
  x0 += ks2; x1 += k0 + 5u;
  o0 = x0; o1 = x1;
#undef TF_RND
#undef TF_ROT
}

__device__ __forceinline__ uint32_t rb32(uint32_t k0, uint32_t k1, uint32_t idx) {
  uint32_t a, b;
  threefry2x32(k0, k1, 0u, idx, a, b);
  return a ^ b;
}

__device__ __forceinline__ float u01_from_bits(uint32_t bits) {
  return __uint_as_float((bits >> 9) | 0x3f800000u) - 1.0f;  // [0,1)
}

// XLA ErfInv32 (Giles single-precision polynomial)
__device__ __forceinline__ float erfinv_f32(float x) {
  float w = -log1pf(-x * x);
  float p;
  if (w < 5.0f) {
    w = w - 2.5f;
    p = 2.81022636e-08f;
    p = fmaf(p, w, 3.43273939e-07f);
    p = fmaf(p, w, -3.5233877e-06f);
    p = fmaf(p, w, -4.39150654e-06f);
    p = fmaf(p, w, 0.00021858087f);
    p = fmaf(p, w, -0.00125372503f);
    p = fmaf(p, w, -0.00417768164f);
    p = fmaf(p, w, 0.246640727f);
    p = fmaf(p, w, 1.50140941f);
  } else {
    w = sqrtf(w) - 3.0f;
    p = -0.000200214257f;
    p = fmaf(p, w, 0.000100950558f);
    p = fmaf(p, w, 0.00134934322f);
    p = fmaf(p, w, -0.00367342844f);
    p = fmaf(p, w, 0.00573950773f);
    p = fmaf(p, w, -0.0076224613f);
    p = fmaf(p, w, 0.00943887047f);
    p = fmaf(p, w, 1.00167406f);
    p = fmaf(p, w, 2.83297682f);
  }
  return p * x;
}

// ---------------- bf16 split helpers (R2-verified) ----------------
__device__ __forceinline__ unsigned short bf16_rne(float x) {
  uint32_t u = __float_as_uint(x);
  uint32_t r = u + 0x7fffu + ((u >> 16) & 1u);
  return (unsigned short)(r >> 16);
}

__device__ __forceinline__ void split2(float x, short& hi, short& lo) {
  unsigned short hb = bf16_rne(x);
  float hf = __uint_as_float((uint32_t)hb << 16);
  hi = (short)hb;
  lo = (short)bf16_rne(x - hf);
}

// ---------------- async global->LDS (16B/lane) ----------------
__device__ __forceinline__ void gload16(const void* g, void* l) {
  __builtin_amdgcn_global_load_lds(
      (const __attribute__((address_space(1))) void*)g,
      (__attribute__((address_space(3))) void*)l, 16, 0, 0);
}

// stage ROWS x 32 bf16 tile (row-major, 64B rows) from global [rows][512]
template <int ROWS>
__device__ __forceinline__ void stage_region(const short* __restrict__ g,
                                             short* l, int wid, int lane) {
#pragma unroll
  for (int c = wid; c < ROWS / 16; c += 4) {
    const short* gp = g + (size_t)(c * 16 + (lane >> 2)) * 512 + (lane & 3) * 8;
    gload16(gp, l + c * 512);
  }
}

// ---------------- prep: xcat = [x*mask, mask]  (bit-identical to R1) ------
__global__ __launch_bounds__(256) void prep_kernel(const float* __restrict__ x,
                                                   const float* __restrict__ mask,
                                                   float* __restrict__ xcat) {
  int i = blockIdx.x * 256 + threadIdx.x;  // over B*512
  if (i >= B * 2 * D) return;
  int b = i >> 9, c = i & 511;
  float v = (c < D) ? x[b * D + c] * mask[b * D + c] : mask[b * D + (c - D)];
  xcat[i] = v;
}

// ---------------- logit weight gather: wsgL[k][c] = Wf[k][(c/10)*94 + c%10]
__global__ __launch_bounds__(256) void wgatherL(const float* __restrict__ Wf,
                                                float* __restrict__ wsgL) {
  int c = blockIdx.x * 256 + threadIdx.x;  // 0..2559
  int k = blockIdx.y;                      // 0..511
  int dd = c / K, j = c - dd * K;
  wsgL[(size_t)k * NLOG + c] = Wf[(size_t)k * (D * HEADW) + dd * HEADW + j];
}

// ---- MS weight transpose + 2-split: Wf[512][24064] -> wms hi/lo [5120][512]
// out row n: dd = n/20, j = n%20, src col dd*94 + 10 + j
__global__ __launch_bounds__(256) void wsplit_ms(const float* __restrict__ Wf,
                                                 short* __restrict__ whi,
                                                 short* __restrict__ wlo) {
  __shared__ float tile[32][33];
  int n0 = blockIdx.x * 32, k0 = blockIdx.y * 32;
  int tx = threadIdx.x & 31, ty = threadIdx.x >> 5;  // 32 x 8
#pragma unroll
  for (int r = 0; r < 4; ++r) {
    int k = k0 + ty + r * 8;
    int n = n0 + tx;
    int dd = n / 20, j = n - dd * 20;
    tile[ty + r * 8][tx] = Wf[(size_t)k * (D * HEADW) + dd * HEADW + 10 + j];
  }
  __syncthreads();
#pragma unroll
  for (int r = 0; r < 4; ++r) {
    int n = n0 + ty + r * 8;
    int k = k0 + tx;
    float v = tile[tx][ty + r * 8];
    short hb, lb;
    split2(v, hb, lb);
    whi[(size_t)n * 512 + k] = hb;
    wlo[(size_t)n * 512 + k] = lb;
  }
}

// ---------------- fp32 trunk GEMM (bit-identical chains to R1) ----------
// C(4096x512) = [relu?](A) @ W(512x512) + bias [+ res]
// 128x64 tile, BK=32, 256 threads, 8x4/thread. One sequential fmaf chain
// per output over ascending k -> bit-identical to R1/R4.
template <int RELU, int RES>
__global__ __launch_bounds__(256) void gemm_trunk(const float* __restrict__ A,
                                                  const float* __restrict__ W,
                                                  const float* __restrict__ bias,
                                                  const float* res, float* C) {
  __shared__ float As[32 * 136];  // [k][m], stride 136 (544B, 16B-aligned)
  __shared__ float Ws[32 * 64];   // [k][n], stride 64
  const int tid = threadIdx.x;
  const int lane = tid & 63, wid = tid >> 6;
  const int tx = tid & 15, ty = tid >> 4;
  const int bm = blockIdx.y * 128, bn = blockIdx.x * 64;
  const int ls = tid & 7, lm = tid >> 3;  // A-load: k-slot, row

  float acc[8][4] = {};

  for (int k0 = 0; k0 < H; k0 += 32) {
    // B: direct global->LDS, [k][n]
#pragma unroll
    for (int c = wid; c < 8; c += 4) {
      gload16(W + (size_t)(k0 + c * 4 + (lane >> 4)) * H + bn + (lane & 15) * 4,
              Ws + c * 256 + lane * 4);
    }
    // A: load float4 along k, transpose into [k][m]
#pragma unroll
    for (int r = 0; r < 4; ++r) {
      int m = lm + 32 * r;
      float4 f = *(const float4*)(A + (size_t)(bm + m) * H + k0 + 4 * ls);
      if (RELU) {
        f.x = fmaxf(f.x, 0.0f); f.y = fmaxf(f.y, 0.0f);
        f.z = fmaxf(f.z, 0.0f); f.w = fmaxf(f.w, 0.0f);
      }
      As[(4 * ls + 0) * 136 + m] = f.x;
      As[(4 * ls + 1) * 136 + m] = f.y;
      As[(4 * ls + 2) * 136 + m] = f.z;
      As[(4 * ls + 3) * 136 + m] = f.w;
    }
    __syncthreads();
#pragma unroll
    for (int kk = 0; kk < 32; ++kk) {
      float a[8], b[4];
      *(float4*)(a + 0) = *(const float4*)(As + kk * 136 + ty * 8);
      *(float4*)(a + 4) = *(const float4*)(As + kk * 136 + ty * 8 + 4);
      *(float4*)(b + 0) = *(const float4*)(Ws + kk * 64 + tx * 4);
#pragma unroll
      for (int i = 0; i < 8; ++i)
#pragma unroll
        for (int j = 0; j < 4; ++j) acc[i][j] = fmaf(a[i], b[j], acc[i][j]);
    }
    __syncthreads();
  }
#pragma unroll
  for (int i = 0; i < 8; ++i) {
    int row = bm + ty * 8 + i;
#pragma unroll
    for (int j = 0; j < 4; ++j) {
      int col = bn + tx * 4 + j;
      float v = acc[i][j] + bias[col];
      if (RES) v = res[(size_t)row * H + col] + v;  // same order as R1
      C[(size_t)row * H + col] = v;
    }
  }
}

// ---------------- fp32 fin-LOGITS GEMM (bit-identical chains) ----------
// head logits (4096 x 2560) = h @ wsgL + bf(logit cols); no softplus.
// 128x128 tile, BK=32, 256 threads, 8x8/thread. R4-proven structure.
__global__ __launch_bounds__(256) void gemm_logits(const float* __restrict__ A,
                                                   const float* __restrict__ Wg,
                                                   const float* __restrict__ bf,
                                                   float* __restrict__ headout) {
  __shared__ float As[32 * 136];  // [k][m]
  __shared__ float Ws[32 * 128];  // [k][n]
  const int tid = threadIdx.x;
  const int lane = tid & 63, wid = tid >> 6;
  const int tx = tid & 15, ty = tid >> 4;
  const int bm = blockIdx.y * 128, bn = blockIdx.x * 128;
  const int ls = tid & 7, lm = tid >> 3;

  float acc[8][8] = {};

  for (int k0 = 0; k0 < H; k0 += 32) {
#pragma unroll
    for (int c = wid; c < 16; c += 4) {
      gload16(Wg + (size_t)(k0 + c * 2 + (lane >> 5)) * NLOG + bn + (lane & 31) * 4,
              Ws + c * 256 + lane * 4);
    }
#pragma unroll
    for (int r = 0; r < 4; ++r) {
      int m = lm + 32 * r;
      float4 f = *(const float4*)(A + (size_t)(bm + m) * H + k0 + 4 * ls);
      As[(4 * ls + 0) * 136 + m] = f.x;
      As[(4 * ls + 1) * 136 + m] = f.y;
      As[(4 * ls + 2) * 136 + m] = f.z;
      As[(4 * ls + 3) * 136 + m] = f.w;
    }
    __syncthreads();
#pragma unroll
    for (int kk = 0; kk < 32; ++kk) {
      float a[8], b[8];
      *(float4*)(a + 0) = *(const float4*)(As + kk * 136 + ty * 8);
      *(float4*)(a + 4) = *(const float4*)(As + kk * 136 + ty * 8 + 4);
      *(float4*)(b + 0) = *(const float4*)(Ws + kk * 128 + tx * 8);
      *(float4*)(b + 4) = *(const float4*)(Ws + kk * 128 + tx * 8 + 4);
#pragma unroll
      for (int i = 0; i < 8; ++i)
#pragma unroll
        for (int j = 0; j < 8; ++j) acc[i][j] = fmaf(a[i], b[j], acc[i][j]);
    }
    __syncthreads();
  }
#pragma unroll
  for (int i = 0; i < 8; ++i) {
    int row = bm + ty * 8 + i;
#pragma unroll
    for (int j = 0; j < 8; ++j) {
      int c = bn + tx * 8 + j;           // 0..2559 logit col
      int dd = c / K, jj = c - dd * K;   // jj < 10 -> never softplus
      float v = acc[i][j] + bf[dd * HEADW + jj];
      headout[(size_t)row * NFIN + dd * NOUT + jj] = v;
    }
  }
}

// ---------------- MS MFMA GEMM (R2-verified fragment/epilogue layout) ----
// head means/scales (4096 x 5120) = h @ wms^T via 3-term bf16x2 split:
// Ahi*Bhi + Ahi*Blo + Alo*Bhi. A split from fp32 h on the fly.
__global__ __launch_bounds__(256) void gemm_ms(const float* __restrict__ A,
                                               const short* __restrict__ Bh,
                                               const short* __restrict__ Bl,
                                               const float* __restrict__ bf,
                                               float* __restrict__ headout) {
  __shared__ short lds[4 * 128 * 32];  // Ah, Al, Bh, Bl (8 KB each)
  const int tid = threadIdx.x;
  const int lane = tid & 63, wid = tid >> 6;
  const int wm = wid >> 1, wn = wid & 1;
  const int bm = blockIdx.y * 128, bn = blockIdx.x * 128;
  const int ls = tid & 7, lm = tid >> 3;

  short* ldsAh = lds;
  short* ldsAl = lds + 4096;
  short* ldsBh = lds + 8192;
  short* ldsBl = lds + 12288;

  const short* gBh = Bh + (size_t)bn * 512;
  const short* gBl = Bl + (size_t)bn * 512;

  f32x16 acc[2][2];
#pragma unroll
  for (int mt = 0; mt < 2; ++mt)
#pragma unroll
    for (int nt = 0; nt < 2; ++nt)
#pragma unroll
      for (int i = 0; i < 16; ++i) acc[mt][nt][i] = 0.0f;

  for (int k0 = 0; k0 < 512; k0 += 32) {
    stage_region<128>(gBh + k0, ldsBh, wid, lane);
    stage_region<128>(gBl + k0, ldsBl, wid, lane);
    // A: load fp32 h, split2, write bf16 rows [m][32]
#pragma unroll
    for (int r = 0; r < 4; ++r) {
      int m = lm + 32 * r;
      float4 f = *(const float4*)(A + (size_t)(bm + m) * H + k0 + 4 * ls);
      short4 h4, l4;
      split2(f.x, h4.x, l4.x); split2(f.y, h4.y, l4.y);
      split2(f.z, h4.z, l4.z); split2(f.w, h4.w, l4.w);
      *(short4*)(ldsAh + m * 32 + 4 * ls) = h4;
      *(short4*)(ldsAl + m * 32 + 4 * ls) = l4;
    }
    __syncthreads();
#pragma unroll
    for (int sub = 0; sub < 2; ++sub) {
      bf16x8 ah[2], al[2], bh[2], bl[2];
#pragma unroll
      for (int mt = 0; mt < 2; ++mt) {
        int r = wm * 64 + mt * 32 + (lane & 31);
        int off = r * 32 + sub * 16 + (lane >> 5) * 8;
        ah[mt] = *(const bf16x8*)(ldsAh + off);
        al[mt] = *(const bf16x8*)(ldsAl + off);
      }
#pragma unroll
      for (int nt = 0; nt < 2; ++nt) {
        int r = wn * 64 + nt * 32 + (lane & 31);
        int off = r * 32 + sub * 16 + (lane >> 5) * 8;
        bh[nt] = *(const bf16x8*)(ldsBh + off);
        bl[nt] = *(const bf16x8*)(ldsBl + off);
      }
#pragma unroll
      for (int mt = 0; mt < 2; ++mt)
#pragma unroll
        for (int nt = 0; nt < 2; ++nt) {
          acc[mt][nt] = __builtin_amdgcn_mfma_f32_32x32x16_bf16(ah[mt], bh[nt], acc[mt][nt], 0, 0, 0);
          acc[mt][nt] = __builtin_amdgcn_mfma_f32_32x32x16_bf16(ah[mt], bl[nt], acc[mt][nt], 0, 0, 0);
          acc[mt][nt] = __builtin_amdgcn_mfma_f32_32x32x16_bf16(al[mt], bh[nt], acc[mt][nt], 0, 0, 0);
        }
    }
    __syncthreads();
  }

#pragma unroll
  for (int mt = 0; mt < 2; ++mt)
#pragma unroll
    for (int nt = 0; nt < 2; ++nt) {
      int col = bn + wn * 64 + nt * 32 + (lane & 31);   // 0..5119
      int rbase = bm + wm * 64 + mt * 32 + 4 * (lane >> 5);
      int dd = col / 20, j = col - dd * 20;             // j<10 mean, j>=10 scale
#pragma unroll
      for (int reg = 0; reg < 16; ++reg) {
        int row = rbase + (reg & 3) + 8 * (reg >> 2);
        float v = acc[mt][nt][reg] + bf[dd * HEADW + 10 + j];
        if (j >= 10) v = (fmaxf(v, 0.0f) + log1pf(expf(-fabsf(v)))) + 0.001f;
        headout[(size_t)row * NFIN + dd * NOUT + 10 + j] = v;
      }
    }
}

// ---------------- fused tail: ll + mean + samples (R1/R4 arithmetic) -----
__global__ __launch_bounds__(256) void fused_tail(const float* __restrict__ head,
                                                  const float* __restrict__ x,
                                                  const float* __restrict__ mask,
                                                  float* __restrict__ out_ll,
                                                  float* __restrict__ out_s,
                                                  float* __restrict__ out_mean,
                                                  uint32_t kc0, uint32_t kc1,
                                                  uint32_t kn0, uint32_t kn1) {
  int idx = blockIdx.x * 256 + threadIdx.x;  // b*D + d
  if (idx >= ND) return;
  int b = idx >> 8, d = idx & (D - 1);
  const float* hp = head + (size_t)idx * NOUT;
  float lg[K], mn[K], sc[K];
#pragma unroll
  for (int k = 0; k < K; ++k) { lg[k] = hp[k]; mn[k] = hp[K + k]; sc[k] = hp[2 * K + k]; }
  float q = 1.0f - mask[idx];
  float xu = x[idx] * q;
  // ---- ll + mean (verbatim R1) ----
  float m = lg[0];
#pragma unroll
  for (int k = 1; k < K; ++k) m = fmaxf(m, lg[k]);
  float e[K];
  float sum = 0.0f;
#pragma unroll
  for (int k = 0; k < K; ++k) { e[k] = expf(lg[k] - m); sum += e[k]; }
  float lse = logf(sum);
  float a[K];
  float amax = -3.402823466e38f;
#pragma unroll
  for (int k = 0; k < K; ++k) {
    float z = (xu - mn[k]) / sc[k];
    float cll = -0.5f * z * z - logf(sc[k]) - 0.9189385332046727f;
    float lw = (lg[k] - m) - lse;
    a[k] = lw + cll;
    amax = fmaxf(amax, a[k]);
  }
  float s2 = 0.0f;
#pragma unroll
  for (int k = 0; k < K; ++k) s2 += expf(a[k] - amax);
  out_ll[idx] = (logf(s2) + amax) * q;
  float pm = 0.0f;
#pragma unroll
  for (int k = 0; k < K; ++k) pm += (e[k] / sum) * mn[k];
  out_mean[idx] = pm * q;
  // ---- samples (same RNG indices as R4's sample_kernel) ----
  for (int s = 0; s < S; ++s) {
    uint32_t t32 = (uint32_t)s * (uint32_t)ND + (uint32_t)idx;
    uint32_t base = t32 * (uint32_t)K;
    int best = 0;
    float vbest = -3.402823466e38f;
#pragma unroll
    for (int k = 0; k < K; ++k) {
      uint32_t bits = rb32(kc0, kc1, base + (uint32_t)k);
      float f = fmaxf(u01_from_bits(bits), 1.17549435e-38f);
      float g = -logf(-logf(f));
      float v = g + lg[k];
      if (v > vbest) { vbest = v; best = k; }
    }
    uint32_t ebits = rb32(kn0, kn1, t32);
    float f = u01_from_bits(ebits);
    float r = f * 2.0f + (-0.99999994f);
    r = fmaxf(r, -0.99999994f);
    float eps = 1.4142135623730951f * erfinv_f32(r);
    out_s[((size_t)b * S + s) * D + d] = (mn[best] + sc[best] * eps) * q;
  }
}

// ---------------- launch ----------------
extern "C" void kernel_launch(void* const* d_in, const int* in_sizes, int n_in,
                              void* d_out, int out_size, void* d_ws, size_t ws_size,
                              hipStream_t stream) {
  const float* x    = (const float*)d_in[0];
  const float* mask = (const float*)d_in[1];
  const float* W_in = (const float*)d_in[2];
  const float* b_in = (const float*)d_in[3];
  const float* W1   = (const float*)d_in[4];
  const float* b1   = (const float*)d_in[5];
  const float* W2   = (const float*)d_in[6];
  const float* b2   = (const float*)d_in[7];
  const float* Wf   = (const float*)d_in[8];
  const float* bf   = (const float*)d_in[9];

  // workspace: head 125,829,120 + h 8,388,608 + wsgL 5,242,880
  //          + wms_h 5,242,880 + wms_l 5,242,880 = 149,946,368 B (fits R1-proven cap)
  char* w = (char*)d_ws;
  float* head  = (float*)w;                     // B*7680 f32
  float* xcat  = head;                          // alias: dead after gemm0
  float* t     = head;                          // alias: dead before fin
  float* h     = (float*)(w + 125829120);       // B*512 f32 (live through fin)
  float* wsgL  = (float*)(w + 134217728);       // 512*2560 f32 logit weights
  short* wms_h = (short*)(w + 139460608);       // 5120*512 bf16
  short* wms_l = (short*)(w + 144703488);       // 5120*512 bf16

  float* out_ll   = (float*)d_out;              // (B,D)
  float* out_s    = out_ll + (size_t)ND;        // (B,S,D)
  float* out_mean = out_s + (size_t)ND * S;     // (B,D)

  // independent weight prep first
  wgatherL<<<dim3(NLOG / 256, 512), 256, 0, stream>>>(Wf, wsgL);
  wsplit_ms<<<dim3(NMS / 32, 512 / 32), 256, 0, stream>>>(Wf, wms_h, wms_l);

  prep_kernel<<<(B * 2 * D) / 256, 256, 0, stream>>>(x, mask, xcat);

  dim3 gtr(H / 64, B / 128);  // (8, 32) = 256 blocks
  gemm_trunk<0, 0><<<gtr, 256, 0, stream>>>(xcat, W_in, b_in, nullptr, h);
  for (int l = 0; l < NL; ++l) {
    gemm_trunk<1, 0><<<gtr, 256, 0, stream>>>(h, W1 + (size_t)l * H * H,
                                              b1 + (size_t)l * H, nullptr, t);
    gemm_trunk<1, 1><<<gtr, 256, 0, stream>>>(t, W2 + (size_t)l * H * H,
                                              b2 + (size_t)l * H, h, h);
  }

  gemm_logits<<<dim3(NLOG / 128, B / 128), 256, 0, stream>>>(h, wsgL, bf, head);
  gemm_ms<<<dim3(NMS / 128, B / 128), 256, 0, stream>>>(h, wms_h, wms_l, bf, head);

  uint32_t kc0, kc1, kn0, kn1;
  threefry2x32(0u, 1234u, 0u, 0u, kc0, kc1);
  threefry2x32(0u, 1234u, 0u, 1u, kn0, kn1);
  fused_tail<<<ND / 256, 256, 0, stream>>>(head, x, mask, out_ll, out_s, out_mean,
                                           kc0, kc1, kn0, kn1);
}